// Round 1
// baseline (1410.089 us; speedup 1.0000x reference)
//
#include <hip/hip_runtime.h>
#include <hip/hip_bf16.h>
#include <math.h>

#define Bb 16
#define DIN 16
#define LL 4096
#define HH 256
#define NN2 32
#define NLAY 4
#define HN (HH*NN2)
#define CHUNK 128
#define NCH (LL/CHUNK)

// ---------------- encoder: h[b,h,l] = sum_i x[b,i,l]*ew[i,h] + eb[h] ----------------
__global__ __launch_bounds__(256) void enc_kernel(const float* __restrict__ x,
    const float* __restrict__ ew, const float* __restrict__ eb,
    float* __restrict__ hbuf) {
  int blk = blockIdx.x;
  int tile = blk & 15;
  int h = (blk >> 4) & (HH - 1);
  int b = blk >> 12;
  int l = tile * 256 + threadIdx.x;
  const float* xb = x + (size_t)b * DIN * LL + l;
  float acc = eb[h];
  #pragma unroll
  for (int i = 0; i < DIN; ++i)
    acc = fmaf(xb[(size_t)i * LL], ew[i * HH + h], acc);
  hbuf[((size_t)(b * HH + h)) * LL + l] = acc;
}

// ---------------- per-layer SSM coefficients ----------------
// coef layout: [0,HN) w_re | [HN,2HN) w_im | [2HN,3HN) 2*Cc_re | [3HN,4HN) 2*Cc_im
__global__ __launch_bounds__(256) void coef_kernel(
    const float* __restrict__ log_dt, const float* __restrict__ Are,
    const float* __restrict__ Aim, const float* __restrict__ Cre,
    const float* __restrict__ Cim, float* __restrict__ coef) {
  int idx = blockIdx.x * 256 + threadIdx.x;
  if (idx >= HN) return;
  int h = idx >> 5;
  float dt = expf(log_dt[h]);
  float ar = -expf(Are[idx]);
  float ai = Aim[idx];
  float dre = ar * dt, dim = ai * dt;
  float er = expf(dre);
  float wr = er * cosf(dim);
  float wi = er * sinf(dim);
  // Cc = C * (exp(dtA)-1)/A
  float nr = wr - 1.f, ni = wi;
  float inv = 1.f / (ar * ar + ai * ai);
  float qr = (nr * ar + ni * ai) * inv;
  float qi = (ni * ar - nr * ai) * inv;
  float crv = Cre[idx], civ = Cim[idx];
  coef[idx]          = wr;
  coef[HN + idx]     = wi;
  coef[2 * HN + idx] = 2.f * (crv * qr - civ * qi);
  coef[3 * HN + idx] = 2.f * (crv * qi + civ * qr);
}

// ---------------- fused SSM: recurrence + skip + gelu, one block per (b,h) ----------------
__global__ __launch_bounds__(256) void s4_kernel(
    const float* __restrict__ zg, const float* __restrict__ coef,
    const float* __restrict__ Dvec, float* __restrict__ gout) {
  __shared__ float z_lds[LL + NCH];   // padded: index l -> l + (l>>7)
  __shared__ float y_lds[LL + NCH];
  __shared__ float st[NCH * NN2 * 2]; // chunk states (finals, then inits)
  int bh = blockIdx.x;
  int h = bh & (HH - 1);
  int t = threadIdx.x;
  const float* zrow = zg + (size_t)bh * LL;
  #pragma unroll
  for (int p = 0; p < 4; ++p) {
    int i4 = p * 256 + t;
    float4 v = ((const float4*)zrow)[i4];
    int l = i4 * 4;
    int base = l + (l >> 7);
    z_lds[base] = v.x; z_lds[base + 1] = v.y; z_lds[base + 2] = v.z; z_lds[base + 3] = v.w;
  }
  __syncthreads();
  int c = t >> 3;       // chunk 0..31
  int sub = t & 7;      // 8 lanes per chunk, 4 n's each
  float wr[4], wi[4], cr[4], ci[4];
  const float* cf = coef + h * NN2;
  #pragma unroll
  for (int k = 0; k < 4; ++k) {
    int n = sub * 4 + k;
    wr[k] = cf[n];
    wi[k] = cf[HN + n];
    cr[k] = cf[2 * HN + n];
    ci[k] = cf[3 * HN + n];
  }
  int zbase = c * (CHUNK + 1);
  // phase 1: chunk-local recurrence (zero init), states only
  float sr[4] = {0.f, 0.f, 0.f, 0.f}, si[4] = {0.f, 0.f, 0.f, 0.f};
  for (int j = 0; j < CHUNK; ++j) {
    float zv = z_lds[zbase + j];
    #pragma unroll
    for (int k = 0; k < 4; ++k) {
      float nr = fmaf(wr[k], sr[k], fmaf(-wi[k], si[k], zv));
      float ni = fmaf(wr[k], si[k], wi[k] * sr[k]);
      sr[k] = nr; si[k] = ni;
    }
  }
  #pragma unroll
  for (int k = 0; k < 4; ++k) {
    int n = sub * 4 + k;
    st[(c * NN2 + n) * 2] = sr[k];
    st[(c * NN2 + n) * 2 + 1] = si[k];
  }
  __syncthreads();
  // phase 2: sequential scan over chunks (32 threads, one per n)
  if (t < NN2) {
    int n = t;
    float pr = coef[h * NN2 + n], pi = coef[HN + h * NN2 + n];
    #pragma unroll
    for (int q = 0; q < 7; ++q) {  // w^128 by squaring
      float nr = pr * pr - pi * pi;
      float ni = 2.f * pr * pi;
      pr = nr; pi = ni;
    }
    float ar = 0.f, ai = 0.f;
    for (int cc = 0; cc < NCH; ++cc) {
      float fr = st[(cc * NN2 + n) * 2], fi = st[(cc * NN2 + n) * 2 + 1];
      st[(cc * NN2 + n) * 2] = ar;
      st[(cc * NN2 + n) * 2 + 1] = ai;
      float nr = fmaf(pr, ar, fmaf(-pi, ai, fr));
      float ni = fmaf(pr, ai, fmaf(pi, ar, fi));
      ar = nr; ai = ni;
    }
  }
  __syncthreads();
  // phase 3: recurrence with correct init + output
  #pragma unroll
  for (int k = 0; k < 4; ++k) {
    int n = sub * 4 + k;
    sr[k] = st[(c * NN2 + n) * 2];
    si[k] = st[(c * NN2 + n) * 2 + 1];
  }
  for (int j = 0; j < CHUNK; ++j) {
    float zv = z_lds[zbase + j];
    float y = 0.f;
    #pragma unroll
    for (int k = 0; k < 4; ++k) {
      float nr = fmaf(wr[k], sr[k], fmaf(-wi[k], si[k], zv));
      float ni = fmaf(wr[k], si[k], wi[k] * sr[k]);
      sr[k] = nr; si[k] = ni;
      y = fmaf(cr[k], nr, fmaf(-ci[k], ni, y));
    }
    y += __shfl_xor(y, 1);
    y += __shfl_xor(y, 2);
    y += __shfl_xor(y, 4);
    if (sub == 0) y_lds[zbase + j] = y;
  }
  __syncthreads();
  // epilogue: skip + gelu(tanh approx), coalesced write
  float Dh = Dvec[h];
  float* grow = gout + (size_t)bh * LL;
  for (int p = 0; p < 16; ++p) {
    int l = p * 256 + t;
    int pl = l + (l >> 7);
    float zv = z_lds[pl];
    float yv = y_lds[pl];
    float v = fmaf(zv, Dh, yv);
    float u = 0.7978845608028654f * fmaf(0.044715f * v, v * v, v);
    grow[l] = 0.5f * v * (1.f + tanhf(u));
  }
}

// ---------------- matmul (256x256) + bias + residual + LayerNorm, in-place h update ----------------
__global__ __launch_bounds__(256) void mm_ln_kernel(
    const float* __restrict__ g_buf, float* __restrict__ h_buf,
    const float* __restrict__ W, const float* __restrict__ bo,
    const float* __restrict__ lw, const float* __restrict__ lb) {
  __shared__ float gt[HH * 32];   // g tile [h][l], stride 32 (broadcast reads)
  __shared__ float ot[HH * 33];   // residual / output tile, stride 33 (conflict-free)
  int blk = blockIdx.x;
  int b = blk >> 7;               // L/32 = 128 tiles per batch
  int l0 = (blk & 127) * 32;
  int t = threadIdx.x;
  const float* gb = g_buf + (size_t)b * HH * LL + l0;
  #pragma unroll
  for (int p = 0; p < 8; ++p) {
    int row = p * 32 + (t >> 3);
    int c4 = (t & 7) * 4;
    float4 v = *(const float4*)(gb + (size_t)row * LL + c4);
    *(float4*)(gt + row * 32 + c4) = v;
  }
  __syncthreads();
  int dd = t & 63;   // d = dd + 64*r
  int lg = t >> 6;   // l = lg*8 + j
  float acc[4][8];
  #pragma unroll
  for (int r = 0; r < 4; ++r)
    #pragma unroll
    for (int j = 0; j < 8; ++j) acc[r][j] = 0.f;
  for (int hh = 0; hh < HH; ++hh) {
    float w0 = W[hh * HH + dd];
    float w1 = W[hh * HH + dd + 64];
    float w2 = W[hh * HH + dd + 128];
    float w3 = W[hh * HH + dd + 192];
    float gv[8];
    #pragma unroll
    for (int j = 0; j < 8; ++j) gv[j] = gt[hh * 32 + lg * 8 + j];
    #pragma unroll
    for (int j = 0; j < 8; ++j) {
      acc[0][j] = fmaf(w0, gv[j], acc[0][j]);
      acc[1][j] = fmaf(w1, gv[j], acc[1][j]);
      acc[2][j] = fmaf(w2, gv[j], acc[2][j]);
      acc[3][j] = fmaf(w3, gv[j], acc[3][j]);
    }
  }
  // stage residual h_in into ot
  const float* hbp = h_buf + (size_t)b * HH * LL + l0;
  #pragma unroll
  for (int p = 0; p < 8; ++p) {
    int row = p * 32 + (t >> 3);
    int c4 = (t & 7) * 4;
    float4 v = *(const float4*)(hbp + (size_t)row * LL + c4);
    float* dst = ot + row * 33 + c4;
    dst[0] = v.x; dst[1] = v.y; dst[2] = v.z; dst[3] = v.w;
  }
  __syncthreads();
  float vv[4][8];
  float bo4[4], lw4[4], lb4[4];
  #pragma unroll
  for (int r = 0; r < 4; ++r) {
    int d = dd + 64 * r;
    bo4[r] = bo[d]; lw4[r] = lw[d]; lb4[r] = lb[d];
  }
  #pragma unroll
  for (int r = 0; r < 4; ++r)
    #pragma unroll
    for (int j = 0; j < 8; ++j)
      vv[r][j] = acc[r][j] + bo4[r] + ot[(dd + 64 * r) * 33 + lg * 8 + j];
  // LN stats: wave-wide butterfly per column (each wave owns 8 columns)
  float mean8[8], rstd8[8];
  #pragma unroll
  for (int j = 0; j < 8; ++j) {
    float s = vv[0][j] + vv[1][j] + vv[2][j] + vv[3][j];
    float q = fmaf(vv[0][j], vv[0][j], fmaf(vv[1][j], vv[1][j],
              fmaf(vv[2][j], vv[2][j], vv[3][j] * vv[3][j])));
    #pragma unroll
    for (int m = 1; m < 64; m <<= 1) {
      s += __shfl_xor(s, m);
      q += __shfl_xor(q, m);
    }
    float mu = s * (1.f / 256.f);
    float var = q * (1.f / 256.f) - mu * mu;
    mean8[j] = mu;
    rstd8[j] = rsqrtf(var + 1e-5f);
  }
  __syncthreads();  // everyone done reading ot
  #pragma unroll
  for (int r = 0; r < 4; ++r)
    #pragma unroll
    for (int j = 0; j < 8; ++j)
      ot[(dd + 64 * r) * 33 + lg * 8 + j] =
          (vv[r][j] - mean8[j]) * rstd8[j] * lw4[r] + lb4[r];
  __syncthreads();
  float* hw = h_buf + (size_t)b * HH * LL + l0;
  for (int p = 0; p < 32; ++p) {
    int idx = p * 256 + t;
    int row = idx >> 5;
    int col = idx & 31;
    hw[(size_t)row * LL + col] = ot[row * 33 + col];
  }
}

// ---------------- decoder: out[b,d,l] = sum_h h[b,h,l]*dw[h,d] + db[d] ----------------
__global__ __launch_bounds__(256) void dec_kernel(
    const float* __restrict__ hbuf, const float* __restrict__ dw,
    const float* __restrict__ db, float* __restrict__ outp) {
  __shared__ float dwl[HH * DIN];
  int blk = blockIdx.x;
  int b = blk >> 4;
  int l0 = (blk & 15) * 256;
  int t = threadIdx.x;
  #pragma unroll
  for (int p = 0; p < 16; ++p) dwl[p * 256 + t] = dw[p * 256 + t];
  __syncthreads();
  float acc[DIN];
  #pragma unroll
  for (int d = 0; d < DIN; ++d) acc[d] = db[d];
  const float* hb = hbuf + (size_t)b * HH * LL + l0;
  for (int hh = 0; hh < HH; ++hh) {
    float v = hb[(size_t)hh * LL + t];
    #pragma unroll
    for (int d = 0; d < DIN; ++d)
      acc[d] = fmaf(v, dwl[hh * DIN + d], acc[d]);
  }
  float* ob = outp + (size_t)b * DIN * LL + l0;
  #pragma unroll
  for (int d = 0; d < DIN; ++d) ob[(size_t)d * LL + t] = acc[d];
}

extern "C" void kernel_launch(void* const* d_in, const int* in_sizes, int n_in,
                              void* d_out, int out_size, void* d_ws, size_t ws_size,
                              hipStream_t stream) {
  const float* x      = (const float*)d_in[0];
  const float* enc_w  = (const float*)d_in[1];
  const float* enc_b  = (const float*)d_in[2];
  const float* log_dt = (const float*)d_in[3];
  const float* A_re   = (const float*)d_in[4];
  const float* A_im   = (const float*)d_in[5];
  const float* C_re   = (const float*)d_in[6];
  const float* C_im   = (const float*)d_in[7];
  const float* Dv     = (const float*)d_in[8];
  const float* W_out  = (const float*)d_in[9];
  const float* b_out  = (const float*)d_in[10];
  const float* ln_w   = (const float*)d_in[11];
  const float* ln_b   = (const float*)d_in[12];
  const float* dec_w  = (const float*)d_in[13];
  const float* dec_b  = (const float*)d_in[14];
  float* out = (float*)d_out;

  float* h_buf = (float*)d_ws;
  float* g_buf = h_buf + (size_t)Bb * HH * LL;
  float* coef  = g_buf + (size_t)Bb * HH * LL;

  enc_kernel<<<Bb * HH * (LL / 256), 256, 0, stream>>>(x, enc_w, enc_b, h_buf);
  for (int i = 0; i < NLAY; ++i) {
    coef_kernel<<<HN / 256, 256, 0, stream>>>(log_dt + i * HH, A_re + i * HN,
                                              A_im + i * HN, C_re + i * HN,
                                              C_im + i * HN, coef);
    s4_kernel<<<Bb * HH, 256, 0, stream>>>(h_buf, coef, Dv + i * HH, g_buf);
    mm_ln_kernel<<<Bb * (LL / 32), 256, 0, stream>>>(
        g_buf, h_buf, W_out + (size_t)i * HH * HH, b_out + i * HH,
        ln_w + i * HH, ln_b + i * HH);
  }
  dec_kernel<<<Bb * (LL / 256), 256, 0, stream>>>(h_buf, dec_w, dec_b, out);
}